// Round 3
// baseline (32537.030 us; speedup 1.0000x reference)
//
#include <hip/hip_runtime.h>
#include <float.h>

// Batched transducer greedy decode, B=32 T=1000 H=640 V=5000, fp32.
// Persistent kernel, 240 blocks x 512 thr, 2 grid barriers/step.
// R3 (on top of R2's validated fence-free sc1 coherence model):
//  - Weights no longer staged in LDS: since L2 is never invalidated anymore,
//    each block's 80KB Wc/Wh slice stays L2-resident; read directly with
//    dwordx4 (Wc cols contiguous; Wh's 8-col subgroups contiguous).
//  - Freed 80KB LDS holds the FULL 640x32 joint/h tile, staged once per step
//    in a single sc1 burst (10 dwordx4/thread, one vmcnt latency shot).
//  - Register-blocked GEMM 8col x 4batch per thread: per k-iter = 1 LDS b128
//    + 2 global b128 + 32 FMA. Cuts phase-A LDS issue from ~13.6us to ~1.6us;
//    phase A becomes VALU-bound (~2.5us).
#define BB 32
#define TT 1000
#define HH 640
#define H4 2560
#define VV 5000
#define NLOG 157   // logits tiles, 32 cols each (last tile 8 valid)
#define NGATE 80   // gate blocks: strided 32-col Wh slice + 8 j-rows of state
#define NB   240   // 8 barrier groups x 30

// workspace layout (float offsets)
#define O_JOINT 0        // jointT[j][b]  (640x32)   cross-block (sc1 path)
#define O_HT    20480    // hT[j][b]      (640x32)   cross-block (sc1 path)
#define O_PM    40960    // partial max    [157*32]  cross-block (sc1 path)
#define O_PS    46080    // partial sumexp [157*32]  cross-block (sc1 path)
#define O_PI    51200    // partial argmax [157*32] (int bits)    (sc1 path)
#define O_BAR   56320    // barrier: 17 slots x 16 u32
#define O_CT    56704    // initial c (640x32) — consumed once at kernel start
#define O_PNT   77184    // initial out_PN (640x32) — consumed once
#define O_XWXB  97664    // embed@Wx + b  (5000x2560), optional
#define XWXB_ELEMS ((size_t)VV * (size_t)H4)

typedef unsigned int u32;
typedef unsigned long long u64;

__device__ __forceinline__ float sigf(float x) { return 1.0f / (1.0f + expf(-x)); }

// ---- sc1 (MALL-coherent, L1/L2-bypassing) scalar access helpers.
__device__ __forceinline__ float ldc1(const float* p) {
  u32 v = __hip_atomic_load((const u32*)p, __ATOMIC_RELAXED, __HIP_MEMORY_SCOPE_AGENT);
  return __uint_as_float(v);
}
__device__ __forceinline__ void stc1(float* p, float x) {
  __hip_atomic_store((u32*)p, __float_as_uint(x), __ATOMIC_RELAXED, __HIP_MEMORY_SCOPE_AGENT);
}

// ---- staged sc1 burst: 20480 floats (5120 float4) global -> LDS, 512 threads,
// ---- 10 dwordx4 loads per thread issued back-to-back, ONE vmcnt wait (one
// ---- MALL latency shot), then stride-1 conflict-free LDS writes.
__device__ __forceinline__ void stage_sc1_full(float* dst, const float* src, int tid) {
  const float* p0 = src + 4 * (tid + 0 * 512);
  const float* p1 = src + 4 * (tid + 1 * 512);
  const float* p2 = src + 4 * (tid + 2 * 512);
  const float* p3 = src + 4 * (tid + 3 * 512);
  const float* p4 = src + 4 * (tid + 4 * 512);
  const float* p5 = src + 4 * (tid + 5 * 512);
  const float* p6 = src + 4 * (tid + 6 * 512);
  const float* p7 = src + 4 * (tid + 7 * 512);
  const float* p8 = src + 4 * (tid + 8 * 512);
  const float* p9 = src + 4 * (tid + 9 * 512);
  float4 a0, a1, a2, a3, a4, a5, a6, a7, a8, a9;
  asm volatile(
      "global_load_dwordx4 %0, %10, off sc0 sc1\n\t"
      "global_load_dwordx4 %1, %11, off sc0 sc1\n\t"
      "global_load_dwordx4 %2, %12, off sc0 sc1\n\t"
      "global_load_dwordx4 %3, %13, off sc0 sc1\n\t"
      "global_load_dwordx4 %4, %14, off sc0 sc1\n\t"
      "global_load_dwordx4 %5, %15, off sc0 sc1\n\t"
      "global_load_dwordx4 %6, %16, off sc0 sc1\n\t"
      "global_load_dwordx4 %7, %17, off sc0 sc1\n\t"
      "global_load_dwordx4 %8, %18, off sc0 sc1\n\t"
      "global_load_dwordx4 %9, %19, off sc0 sc1\n\t"
      "s_waitcnt vmcnt(0)"
      : "=&v"(a0), "=&v"(a1), "=&v"(a2), "=&v"(a3), "=&v"(a4),
        "=&v"(a5), "=&v"(a6), "=&v"(a7), "=&v"(a8), "=&v"(a9)
      : "v"(p0), "v"(p1), "v"(p2), "v"(p3), "v"(p4),
        "v"(p5), "v"(p6), "v"(p7), "v"(p8), "v"(p9)
      : "memory");
  float4* d4 = (float4*)dst;
  d4[tid + 0 * 512] = a0;
  d4[tid + 1 * 512] = a1;
  d4[tid + 2 * 512] = a2;
  d4[tid + 3 * 512] = a3;
  d4[tid + 4 * 512] = a4;
  d4[tid + 5 * 512] = a5;
  d4[tid + 6 * 512] = a6;
  d4[tid + 7 * 512] = a7;
  d4[tid + 8 * 512] = a8;
  d4[tid + 9 * 512] = a9;
}

// grid barrier: fence-free. All cross-block data flows through sc1 accesses
// (MALL is memory-side and coherent across XCDs), so no cache maintenance.
__device__ __forceinline__ void grid_bar(unsigned* bar, unsigned target) {
  __syncthreads();
  if (threadIdx.x == 0) {
    const int g = (int)blockIdx.x / 30;
    unsigned* cnt  = bar + g * 16;
    unsigned* gen  = bar + (9 + g) * 16;
    asm volatile("s_waitcnt vmcnt(0)" ::: "memory");
    unsigned a = __hip_atomic_fetch_add(cnt, 1u, __ATOMIC_RELAXED, __HIP_MEMORY_SCOPE_AGENT);
    if (a == 29u) {
      unsigned* root = bar + 8 * 16;
      unsigned r = __hip_atomic_fetch_add(root, 1u, __ATOMIC_RELAXED, __HIP_MEMORY_SCOPE_AGENT);
      if (r == 7u) {
        __hip_atomic_store(root, 0u, __ATOMIC_RELAXED, __HIP_MEMORY_SCOPE_AGENT);
#pragma unroll
        for (int i = 0; i < 8; ++i)
          __hip_atomic_store(bar + i * 16, 0u, __ATOMIC_RELAXED, __HIP_MEMORY_SCOPE_AGENT);
        // resets must be globally visible before the generation release
        asm volatile("s_waitcnt vmcnt(0)" ::: "memory");
#pragma unroll
        for (int i = 0; i < 8; ++i)
          __hip_atomic_store(bar + (9 + i) * 16, target, __ATOMIC_RELAXED, __HIP_MEMORY_SCOPE_AGENT);
      }
    }
    while (__hip_atomic_load(gen, __ATOMIC_RELAXED, __HIP_MEMORY_SCOPE_AGENT) < target)
      __builtin_amdgcn_s_sleep(1);
  }
  __syncthreads();
}

// ---------------- precompute: xwxb[v][c] = sum_k embed[v][k]*Wx[k][c] + b[c]
__global__ __launch_bounds__(256) void precompute_k(const float* __restrict__ embed,
                                                    const float* __restrict__ Wx,
                                                    const float* __restrict__ bias,
                                                    float* __restrict__ xwxb) {
  __shared__ float embT[HH * 17];
  const int tid = threadIdx.x;
  const int v0 = blockIdx.y * 16;
  const int c0 = blockIdx.x * 256 + (tid & 63) * 4;
  const int vg = tid >> 6;
  for (int i = tid; i < 16 * 160; i += 256) {
    int vr = i / 160, kq = i - vr * 160;
    int v = v0 + vr; if (v >= VV) v = VV - 1;
    float4 e = *(const float4*)&embed[(size_t)v * HH + kq * 4];
    embT[(kq * 4 + 0) * 17 + vr] = e.x;
    embT[(kq * 4 + 1) * 17 + vr] = e.y;
    embT[(kq * 4 + 2) * 17 + vr] = e.z;
    embT[(kq * 4 + 3) * 17 + vr] = e.w;
  }
  __syncthreads();
  float acc[16];
#pragma unroll
  for (int i = 0; i < 16; ++i) acc[i] = 0.f;
#pragma unroll 4
  for (int k = 0; k < HH; ++k) {
    float4 wv = *(const float4*)&Wx[(size_t)k * H4 + c0];
#pragma unroll
    for (int i = 0; i < 4; ++i) {
      float e = embT[k * 17 + vg * 4 + i];
      acc[i * 4 + 0] += e * wv.x;
      acc[i * 4 + 1] += e * wv.y;
      acc[i * 4 + 2] += e * wv.z;
      acc[i * 4 + 3] += e * wv.w;
    }
  }
  float4 bv = *(const float4*)&bias[c0];
#pragma unroll
  for (int i = 0; i < 4; ++i) {
    int v = v0 + vg * 4 + i;
    if (v < VV) {
      float4 r;
      r.x = acc[i * 4 + 0] + bv.x; r.y = acc[i * 4 + 1] + bv.y;
      r.z = acc[i * 4 + 2] + bv.z; r.w = acc[i * 4 + 3] + bv.w;
      *(float4*)&xwxb[(size_t)v * H4 + c0] = r;
    }
  }
}

// ---------------- init: barrier zero + initial LSTM step (h0=c0=0, tok=0) + joint t=0
__global__ __launch_bounds__(256) void init_k(const float* __restrict__ tn,
                                              const float* __restrict__ embed,
                                              const float* __restrict__ Wx,
                                              const float* __restrict__ bias,
                                              float* ws, int use_table) {
  const int tid = threadIdx.x, bid = blockIdx.x;
  const int b = tid & 31, c8 = tid >> 5;
  const int j = bid * 8 + c8;
  if (bid == 0) {
    unsigned* bar = (unsigned*)(ws + O_BAR);
    for (int i = tid; i < 17 * 16; i += 256) bar[i] = 0u;
  }
  const float* xwxb = ws + O_XWXB;
  float g4[4];
  if (use_table) {
#pragma unroll
    for (int g = 0; g < 4; ++g) g4[g] = xwxb[g * HH + j];  // token 0 row
  } else {
#pragma unroll
    for (int g = 0; g < 4; ++g) g4[g] = bias[g * HH + j];
#pragma unroll 4
    for (int k = 0; k < HH; ++k) {
      float xv = embed[k];  // token 0 row
#pragma unroll
      for (int g = 0; g < 4; ++g) g4[g] += xv * Wx[(size_t)k * H4 + g * HH + j];
    }
  }
  float c1 = sigf(g4[0]) * tanhf(g4[2]);
  float h1 = sigf(g4[3]) * tanhf(c1);
  ws[O_CT + j * 32 + b] = c1;
  ws[O_HT + j * 32 + b] = h1;
  ws[O_PNT + j * 32 + b] = h1;
  ws[O_JOINT + j * 32 + b] = tanhf(tn[(size_t)b * TT * HH + j] + h1);
}

// ---------------- persistent decode kernel
__global__ __launch_bounds__(512) void decode_k(const float* __restrict__ tn,
                                                const float* __restrict__ embed,
                                                const float* __restrict__ Wx,
                                                const float* __restrict__ bias,
                                                const float* __restrict__ Wh,
                                                const float* __restrict__ Wc,
                                                const float* __restrict__ bc,
                                                float* __restrict__ out,
                                                float* ws, int use_table) {
  __shared__ float joint_s[20480];  // 80 KB: full 640x32 joint/h tile (per step)
  __shared__ float smem[10800];     // scratch overlay: part[8][32*36] / reduce / B scratch
  __shared__ float hwh_s[1056];     // gate: hwh[lc(32) stride 33][b]  (persists A->B)
  __shared__ float c_s[256];        // gate: c state (LDS-resident)
  __shared__ float pn_s[256];       // gate: out_PN state
  __shared__ int s_tok[32];
  __shared__ int s_upd[32];
  __shared__ int s_ptok[32];
  __shared__ float s_scores[32];
  const int tid = threadIdx.x, bid = blockIdx.x;
  unsigned* bar = (unsigned*)(ws + O_BAR);
  const float* xwxb = ws + O_XWXB;
  const bool is_log = (bid < NLOG);
  const bool is_gate = (bid >= NLOG) && (bid < NLOG + NGATE);
  const int q = bid - NLOG;  // gate slice index

  if (tid < 32) { s_ptok[tid] = 0; s_scores[tid] = 0.f; }
  if (is_gate && tid < 256) {
    const int jj = tid >> 5, b = tid & 31;
    c_s[jj * 32 + b] = ws[O_CT + (q * 8 + jj) * 32 + b];
    pn_s[jj * 32 + b] = ws[O_PNT + (q * 8 + jj) * 32 + b];
  }
  __syncthreads();

  // ---- GEMM thread decomposition: 8 cols x 4 batches per thread, 16-way K split
  const int lane = tid & 63, wvv = tid >> 6;
  const int sub = lane >> 5;          // K-split parity
  const int cg  = lane & 3;           // 4 col-groups of 8 contiguous cols
  const int bg  = (lane >> 2) & 7;    // 8 batch-groups of 4
  const int kb  = (wvv * 2 + sub) * 40;  // this thread's 40-row K chunk
  // weight base pointer (L2-resident, plain cached loads) + row stride
  const float* wbase;
  int wstride;
  if (is_log) {
    int c = bid * 32 + cg * 8;
    if (c > VV - 8) c = VV - 8;   // clamp (dup cols; masked at logits stage)
    wbase = Wc + (size_t)kb * VV + c;
    wstride = VV;
  } else {
    wbase = Wh + (size_t)kb * H4 + cg * HH + q * 8;
    wstride = H4;
  }
  const float* jb0 = joint_s + kb * 32 + bg * 4;

  unsigned epoch = 0;
  for (int t = 0; t < TT; ++t) {
    float tnv = 0.f;  // gate: tn[b][t+1][8q+jj], prefetched (held across barrier 1)

    // ================= phase A =================
    if (is_log || is_gate) {
      if (is_gate && tid < 256 && t + 1 < TT)
        tnv = tn[((size_t)(tid & 31) * TT + (t + 1)) * HH + q * 8 + (tid >> 5)];
      // stage the full 640x32 tile: one sc1 burst, one latency shot
      stage_sc1_full(joint_s, ws + (is_log ? O_JOINT : O_HT), tid);
      __syncthreads();

      float acc[32];  // acc[c*4+b]: 8 cols x 4 batches
#pragma unroll
      for (int i = 0; i < 32; ++i) acc[i] = 0.f;
      {
        const float* wp = wbase;
        const float* jp = jb0;
#pragma unroll 4
        for (int kk = 0; kk < 40; ++kk) {
          float4 w0 = *(const float4*)(wp);
          float4 w1 = *(const float4*)(wp + 4);
          float4 jv = *(const float4*)(jp);
          wp += wstride;
          jp += 32;
          acc[0]  += w0.x * jv.x; acc[1]  += w0.x * jv.y; acc[2]  += w0.x * jv.z; acc[3]  += w0.x * jv.w;
          acc[4]  += w0.y * jv.x; acc[5]  += w0.y * jv.y; acc[6]  += w0.y * jv.z; acc[7]  += w0.y * jv.w;
          acc[8]  += w0.z * jv.x; acc[9]  += w0.z * jv.y; acc[10] += w0.z * jv.z; acc[11] += w0.z * jv.w;
          acc[12] += w0.w * jv.x; acc[13] += w0.w * jv.y; acc[14] += w0.w * jv.z; acc[15] += w0.w * jv.w;
          acc[16] += w1.x * jv.x; acc[17] += w1.x * jv.y; acc[18] += w1.x * jv.z; acc[19] += w1.x * jv.w;
          acc[20] += w1.y * jv.x; acc[21] += w1.y * jv.y; acc[22] += w1.y * jv.z; acc[23] += w1.y * jv.w;
          acc[24] += w1.z * jv.x; acc[25] += w1.z * jv.y; acc[26] += w1.z * jv.z; acc[27] += w1.z * jv.w;
          acc[28] += w1.w * jv.x; acc[29] += w1.w * jv.y; acc[30] += w1.w * jv.z; acc[31] += w1.w * jv.w;
        }
      }
      // combine K-split pairs (sub 0/1) within the wave
#pragma unroll
      for (int i = 0; i < 32; ++i) acc[i] += __shfl_xor(acc[i], 32);
      float* part = smem;  // [8 waves][32 cols * 36]
      if (sub == 0) {
        float* pb = part + wvv * 1152 + bg * 4;
#pragma unroll
        for (int c = 0; c < 8; ++c)
          *(float4*)&pb[(cg * 8 + c) * 36] =
              make_float4(acc[c * 4 + 0], acc[c * 4 + 1], acc[c * 4 + 2], acc[c * 4 + 3]);
      }
      __syncthreads();

      const int b = tid & 31, colg = tid >> 5;
      if (is_log) {
        float* lm = smem + 9216;
        float* lsv = smem + 9744;
        int* lix = (int*)(smem + 10272);
        float m = -FLT_MAX; int ix = 0;
        float lv[2];
#pragma unroll
        for (int i = 0; i < 2; ++i) {
          const int cl = colg * 2 + i;
          float s = 0.f;
#pragma unroll
          for (int qq = 0; qq < 8; ++qq) s += part[qq * 1152 + cl * 36 + b];
          int cgl = bid * 32 + cl;
          float l = (cgl < VV) ? s + bc[cgl] : -FLT_MAX;
          lv[i] = l;
          if (l > m) { m = l; ix = cgl; }
        }
        float e = 0.f;
        if (m > -FLT_MAX) {
#pragma unroll
          for (int i = 0; i < 2; ++i) e += expf(lv[i] - m);
        }
        lm[colg * 33 + b] = m; lsv[colg * 33 + b] = e; lix[colg * 33 + b] = ix;
        __syncthreads();
        if (tid < 32) {
          float m2 = lm[tid], s2 = lsv[tid]; int ix2 = lix[tid];
#pragma unroll
          for (int qq = 1; qq < 16; ++qq) {
            float M = lm[qq * 33 + tid], S = lsv[qq * 33 + tid]; int I = lix[qq * 33 + tid];
            if (M > m2) { s2 = s2 * expf(m2 - M) + S; m2 = M; ix2 = I; }
            else if (M > -FLT_MAX) { s2 += S * expf(M - m2); }
          }
          stc1(&ws[O_PM + bid * 32 + tid], m2);                    // sc1 write-through
          stc1(&ws[O_PS + bid * 32 + tid], s2);
          stc1(&ws[O_PI + bid * 32 + tid], __int_as_float(ix2));
        }
      } else {
#pragma unroll
        for (int i = 0; i < 2; ++i) {
          const int cl = colg * 2 + i;
          float s = 0.f;
#pragma unroll
          for (int qq = 0; qq < 8; ++qq) s += part[qq * 1152 + cl * 36 + b];
          hwh_s[cl * 33 + b] = s;  // stays in LDS — no global round-trip
        }
      }
    }
    epoch++;
    grid_bar(bar, epoch);  // gate blocks read partials next (sc1 loads; no acquire)

    // ================= phase B (gate blocks only) =================
    if (is_gate) {
      float* rm = smem;               // [16*33]
      float* rs = smem + 528;
      int* ri = (int*)(smem + 1056);
      float* gmat = smem + 1584;      // [32*33]
      float* xl = smem + 2640;        // [32*161] fallback staging
      const int r = tid & 31, c16 = tid >> 5;
      {
        float m = -FLT_MAX, s = 0.f; int ix = 0;
#pragma unroll
        for (int i = 0; i < 10; ++i) {
          int idx = c16 * 10 + i;
          bool v = (idx < NLOG);
          int ic = v ? idx : 0;
          float M = ldc1(&ws[O_PM + ic * 32 + r]);               // sc1 reads
          float S = ldc1(&ws[O_PS + ic * 32 + r]);
          int I = __float_as_int(ldc1(&ws[O_PI + ic * 32 + r]));
          if (!v) { M = -FLT_MAX; S = 0.f; I = 0; }
          if (M > m) { s = s * expf(m - M) + S; m = M; ix = I; }
          else if (M > -FLT_MAX) { s += S * expf(M - m); }
        }
        rm[c16 * 33 + r] = m; rs[c16 * 33 + r] = s; ri[c16 * 33 + r] = ix;
      }
      __syncthreads();
      if (tid < 32) {
        float m = rm[tid], s = rs[tid]; int ix = ri[tid];
#pragma unroll
        for (int qq = 1; qq < 16; ++qq) {
          float M = rm[qq * 33 + tid], S = rs[qq * 33 + tid]; int I = ri[qq * 33 + tid];
          if (M > m) { s = s * expf(m - M) + S; m = M; ix = I; }
          else { s += S * expf(M - m); }
        }
        int pos = ix;
        int upd = (pos != 0) ? 1 : 0;
        int ntk = upd ? pos : s_ptok[tid];
        s_tok[tid] = ntk; s_upd[tid] = upd; s_ptok[tid] = ntk;
        if (bid == NLOG) {  // emitter
          float sc = s_scores[tid];
          if (upd) sc -= logf(s);
          s_scores[tid] = sc;
          out[BB + (size_t)tid * TT + t] = upd ? (float)pos : 0.0f;
          if (t == TT - 1) out[tid] = sc;
        }
      }
      __syncthreads();

      // gate pre-activations for the block's 32 strided cols
      const int b = tid & 31;
      float gv[2];
#pragma unroll
      for (int h = 0; h < 2; ++h) {
        int lc = (tid >> 5) + h * 16;
        int wcol = (lc >> 3) * HH + q * 8 + (lc & 7);
        float v = hwh_s[lc * 33 + b];
        if (use_table) v += xwxb[(size_t)s_tok[b] * H4 + wcol];
        else v += bias[wcol];
        gv[h] = v;
      }
      if (!use_table) {
        for (int st = 0; st < 4; ++st) {
          const int k0 = st * 160;
          __syncthreads();
          for (int i = tid; i < 32 * 160; i += 512) {
            int bb = i / 160, kk = i - bb * 160;
            xl[bb * 161 + kk] = embed[(size_t)s_tok[bb] * HH + k0 + kk];
          }
          __syncthreads();
          for (int k = 0; k < 160; ++k) {
            float xv = xl[b * 161 + k];
#pragma unroll
            for (int h = 0; h < 2; ++h) {
              int lc = (tid >> 5) + h * 16;
              int wcol = (lc >> 3) * HH + q * 8 + (lc & 7);
              gv[h] += xv * Wx[(size_t)(k0 + k) * H4 + wcol];
            }
          }
        }
      }
#pragma unroll
      for (int h = 0; h < 2; ++h) {
        int lc = (tid >> 5) + h * 16;
        gmat[lc * 33 + b] = gv[h];
      }
      __syncthreads();
      if (tid < 256) {
        const int jj = tid >> 5, b2 = tid & 31;
        float gi = gmat[(0 * 8 + jj) * 33 + b2];
        float gf = gmat[(1 * 8 + jj) * 33 + b2];
        float gg = gmat[(2 * 8 + jj) * 33 + b2];
        float go = gmat[(3 * 8 + jj) * 33 + b2];
        float cold = c_s[jj * 32 + b2];
        float c2 = sigf(gf) * cold + sigf(gi) * tanhf(gg);
        float h2 = sigf(go) * tanhf(c2);
        float pv;
        if (s_upd[b2]) {
          c_s[jj * 32 + b2] = c2;
          pn_s[jj * 32 + b2] = h2;
          stc1(&ws[O_HT + (q * 8 + jj) * 32 + b2], h2);   // sc1 write-through
          pv = h2;
        } else {
          pv = pn_s[jj * 32 + b2];
        }
        if (t + 1 < TT)
          stc1(&ws[O_JOINT + (q * 8 + jj) * 32 + b2], tanhf(tnv + pv));  // sc1
      }
    }
    epoch++;
    grid_bar(bar, epoch);  // next A stages jointT / hT (sc1 bursts; no acquire)
  }
}

extern "C" void kernel_launch(void* const* d_in, const int* in_sizes, int n_in,
                              void* d_out, int out_size, void* d_ws, size_t ws_size,
                              hipStream_t stream) {
  const float* tn    = (const float*)d_in[0];
  const float* embed = (const float*)d_in[1];
  const float* Wx    = (const float*)d_in[2];
  const float* Wh    = (const float*)d_in[3];
  const float* bias  = (const float*)d_in[4];
  const float* Wc    = (const float*)d_in[5];
  const float* bc    = (const float*)d_in[6];
  float* out = (float*)d_out;
  float* ws  = (float*)d_ws;

  const size_t need_table = (size_t)(O_XWXB + XWXB_ELEMS) * sizeof(float);
  const int use_table = (ws_size >= need_table) ? 1 : 0;

  if (use_table)
    hipLaunchKernelGGL(precompute_k, dim3(10, 313), dim3(256), 0, stream,
                       embed, Wx, bias, ws + O_XWXB);
  hipLaunchKernelGGL(init_k, dim3(80), dim3(256), 0, stream, tn, embed, Wx, bias, ws, use_table);
  hipLaunchKernelGGL(decode_k, dim3(NB), dim3(512), 0, stream,
                     tn, embed, Wx, bias, Wh, Wc, bc, out, ws, use_table);
}

// Round 4
// 23748.611 us; speedup vs baseline: 1.3701x; 1.3701x over previous
//
#include <hip/hip_runtime.h>
#include <float.h>

// Batched transducer greedy decode, B=32 T=1000 H=640 V=5000, fp32.
// Persistent kernel, 240 blocks x 512 thr, 2 grid barriers/step.
// R4 (on top of R3): fix weight L2 residency. R3's rocprof showed FETCH_SIZE
// 1.6GB->25.4GB: gate blocks' strided Wh slices waste 4x line granularity
// (32B used per 128B line), pushing per-XCD weight footprint to ~4.9MB > 4MiB
// L2 -> thrash -> every inner-loop weight load is an HBM-latency miss.
// Fix: repack Wh once into workspace as WhP[q][640][32] (dense 80KB per gate
// slice, exact 128B lines). Per-XCD footprint drops to 2.4MB < 4MiB -> weight
// reads become L2 hits. Guarded by ws_size (falls back to R3 path if absent).
#define BB 32
#define TT 1000
#define HH 640
#define H4 2560
#define VV 5000
#define NLOG 157   // logits tiles, 32 cols each (last tile 8 valid)
#define NGATE 80   // gate blocks: strided 32-col Wh slice + 8 j-rows of state
#define NB   240   // 8 barrier groups x 30

// workspace layout (float offsets)
#define O_JOINT 0        // jointT[j][b]  (640x32)   cross-block (sc1 path)
#define O_HT    20480    // hT[j][b]      (640x32)   cross-block (sc1 path)
#define O_PM    40960    // partial max    [157*32]  cross-block (sc1 path)
#define O_PS    46080    // partial sumexp [157*32]  cross-block (sc1 path)
#define O_PI    51200    // partial argmax [157*32] (int bits)    (sc1 path)
#define O_BAR   56320    // barrier: 17 slots x 16 u32
#define O_CT    56704    // initial c (640x32) — consumed once at kernel start
#define O_PNT   77184    // initial out_PN (640x32) — consumed once
#define O_XWXB  97664    // embed@Wx + b  (5000x2560), optional
#define XWXB_ELEMS ((size_t)VV * (size_t)H4)
#define O_WHP   (O_XWXB + 12800000)   // repacked Wh: [80][640][32], optional
#define WHP_ELEMS ((size_t)NGATE * HH * 32)

typedef unsigned int u32;
typedef unsigned long long u64;

__device__ __forceinline__ float sigf(float x) { return 1.0f / (1.0f + expf(-x)); }

// ---- sc1 (MALL-coherent, L1/L2-bypassing) scalar access helpers.
__device__ __forceinline__ float ldc1(const float* p) {
  u32 v = __hip_atomic_load((const u32*)p, __ATOMIC_RELAXED, __HIP_MEMORY_SCOPE_AGENT);
  return __uint_as_float(v);
}
__device__ __forceinline__ void stc1(float* p, float x) {
  __hip_atomic_store((u32*)p, __float_as_uint(x), __ATOMIC_RELAXED, __HIP_MEMORY_SCOPE_AGENT);
}

// ---- staged sc1 burst: 20480 floats (5120 float4) global -> LDS, 512 threads,
// ---- 10 dwordx4 loads per thread issued back-to-back, ONE vmcnt wait (one
// ---- MALL latency shot), then stride-1 conflict-free LDS writes.
__device__ __forceinline__ void stage_sc1_full(float* dst, const float* src, int tid) {
  const float* p0 = src + 4 * (tid + 0 * 512);
  const float* p1 = src + 4 * (tid + 1 * 512);
  const float* p2 = src + 4 * (tid + 2 * 512);
  const float* p3 = src + 4 * (tid + 3 * 512);
  const float* p4 = src + 4 * (tid + 4 * 512);
  const float* p5 = src + 4 * (tid + 5 * 512);
  const float* p6 = src + 4 * (tid + 6 * 512);
  const float* p7 = src + 4 * (tid + 7 * 512);
  const float* p8 = src + 4 * (tid + 8 * 512);
  const float* p9 = src + 4 * (tid + 9 * 512);
  float4 a0, a1, a2, a3, a4, a5, a6, a7, a8, a9;
  asm volatile(
      "global_load_dwordx4 %0, %10, off sc0 sc1\n\t"
      "global_load_dwordx4 %1, %11, off sc0 sc1\n\t"
      "global_load_dwordx4 %2, %12, off sc0 sc1\n\t"
      "global_load_dwordx4 %3, %13, off sc0 sc1\n\t"
      "global_load_dwordx4 %4, %14, off sc0 sc1\n\t"
      "global_load_dwordx4 %5, %15, off sc0 sc1\n\t"
      "global_load_dwordx4 %6, %16, off sc0 sc1\n\t"
      "global_load_dwordx4 %7, %17, off sc0 sc1\n\t"
      "global_load_dwordx4 %8, %18, off sc0 sc1\n\t"
      "global_load_dwordx4 %9, %19, off sc0 sc1\n\t"
      "s_waitcnt vmcnt(0)"
      : "=&v"(a0), "=&v"(a1), "=&v"(a2), "=&v"(a3), "=&v"(a4),
        "=&v"(a5), "=&v"(a6), "=&v"(a7), "=&v"(a8), "=&v"(a9)
      : "v"(p0), "v"(p1), "v"(p2), "v"(p3), "v"(p4),
        "v"(p5), "v"(p6), "v"(p7), "v"(p8), "v"(p9)
      : "memory");
  float4* d4 = (float4*)dst;
  d4[tid + 0 * 512] = a0;
  d4[tid + 1 * 512] = a1;
  d4[tid + 2 * 512] = a2;
  d4[tid + 3 * 512] = a3;
  d4[tid + 4 * 512] = a4;
  d4[tid + 5 * 512] = a5;
  d4[tid + 6 * 512] = a6;
  d4[tid + 7 * 512] = a7;
  d4[tid + 8 * 512] = a8;
  d4[tid + 9 * 512] = a9;
}

// grid barrier: fence-free. All cross-block data flows through sc1 accesses
// (MALL is memory-side and coherent across XCDs), so no cache maintenance.
__device__ __forceinline__ void grid_bar(unsigned* bar, unsigned target) {
  __syncthreads();
  if (threadIdx.x == 0) {
    const int g = (int)blockIdx.x / 30;
    unsigned* cnt  = bar + g * 16;
    unsigned* gen  = bar + (9 + g) * 16;
    asm volatile("s_waitcnt vmcnt(0)" ::: "memory");
    unsigned a = __hip_atomic_fetch_add(cnt, 1u, __ATOMIC_RELAXED, __HIP_MEMORY_SCOPE_AGENT);
    if (a == 29u) {
      unsigned* root = bar + 8 * 16;
      unsigned r = __hip_atomic_fetch_add(root, 1u, __ATOMIC_RELAXED, __HIP_MEMORY_SCOPE_AGENT);
      if (r == 7u) {
        __hip_atomic_store(root, 0u, __ATOMIC_RELAXED, __HIP_MEMORY_SCOPE_AGENT);
#pragma unroll
        for (int i = 0; i < 8; ++i)
          __hip_atomic_store(bar + i * 16, 0u, __ATOMIC_RELAXED, __HIP_MEMORY_SCOPE_AGENT);
        // resets must be globally visible before the generation release
        asm volatile("s_waitcnt vmcnt(0)" ::: "memory");
#pragma unroll
        for (int i = 0; i < 8; ++i)
          __hip_atomic_store(bar + (9 + i) * 16, target, __ATOMIC_RELAXED, __HIP_MEMORY_SCOPE_AGENT);
      }
    }
    while (__hip_atomic_load(gen, __ATOMIC_RELAXED, __HIP_MEMORY_SCOPE_AGENT) < target)
      __builtin_amdgcn_s_sleep(1);
  }
  __syncthreads();
}

// ---------------- precompute: xwxb[v][c] = sum_k embed[v][k]*Wx[k][c] + b[c]
__global__ __launch_bounds__(256) void precompute_k(const float* __restrict__ embed,
                                                    const float* __restrict__ Wx,
                                                    const float* __restrict__ bias,
                                                    float* __restrict__ xwxb) {
  __shared__ float embT[HH * 17];
  const int tid = threadIdx.x;
  const int v0 = blockIdx.y * 16;
  const int c0 = blockIdx.x * 256 + (tid & 63) * 4;
  const int vg = tid >> 6;
  for (int i = tid; i < 16 * 160; i += 256) {
    int vr = i / 160, kq = i - vr * 160;
    int v = v0 + vr; if (v >= VV) v = VV - 1;
    float4 e = *(const float4*)&embed[(size_t)v * HH + kq * 4];
    embT[(kq * 4 + 0) * 17 + vr] = e.x;
    embT[(kq * 4 + 1) * 17 + vr] = e.y;
    embT[(kq * 4 + 2) * 17 + vr] = e.z;
    embT[(kq * 4 + 3) * 17 + vr] = e.w;
  }
  __syncthreads();
  float acc[16];
#pragma unroll
  for (int i = 0; i < 16; ++i) acc[i] = 0.f;
#pragma unroll 4
  for (int k = 0; k < HH; ++k) {
    float4 wv = *(const float4*)&Wx[(size_t)k * H4 + c0];
#pragma unroll
    for (int i = 0; i < 4; ++i) {
      float e = embT[k * 17 + vg * 4 + i];
      acc[i * 4 + 0] += e * wv.x;
      acc[i * 4 + 1] += e * wv.y;
      acc[i * 4 + 2] += e * wv.z;
      acc[i * 4 + 3] += e * wv.w;
    }
  }
  float4 bv = *(const float4*)&bias[c0];
#pragma unroll
  for (int i = 0; i < 4; ++i) {
    int v = v0 + vg * 4 + i;
    if (v < VV) {
      float4 r;
      r.x = acc[i * 4 + 0] + bv.x; r.y = acc[i * 4 + 1] + bv.y;
      r.z = acc[i * 4 + 2] + bv.z; r.w = acc[i * 4 + 3] + bv.w;
      *(float4*)&xwxb[(size_t)v * H4 + c0] = r;
    }
  }
}

// ---------------- repack Wh into dense per-gate-slice layout (once)
// WhP[q][k][lc] = Wh[k][(lc>>3)*HH + q*8 + (lc&7)]  -> 80KB dense per gate q.
__global__ __launch_bounds__(256) void repack_k(const float* __restrict__ Wh,
                                                float* __restrict__ whp) {
  const int q = blockIdx.x;
  for (int i = threadIdx.x; i < HH * 32; i += 256) {
    int k = i >> 5, lc = i & 31;
    whp[((size_t)q * HH + k) * 32 + lc] =
        Wh[(size_t)k * H4 + (lc >> 3) * HH + q * 8 + (lc & 7)];
  }
}

// ---------------- init: barrier zero + initial LSTM step (h0=c0=0, tok=0) + joint t=0
__global__ __launch_bounds__(256) void init_k(const float* __restrict__ tn,
                                              const float* __restrict__ embed,
                                              const float* __restrict__ Wx,
                                              const float* __restrict__ bias,
                                              float* ws, int use_table) {
  const int tid = threadIdx.x, bid = blockIdx.x;
  const int b = tid & 31, c8 = tid >> 5;
  const int j = bid * 8 + c8;
  if (bid == 0) {
    unsigned* bar = (unsigned*)(ws + O_BAR);
    for (int i = tid; i < 17 * 16; i += 256) bar[i] = 0u;
  }
  const float* xwxb = ws + O_XWXB;
  float g4[4];
  if (use_table) {
#pragma unroll
    for (int g = 0; g < 4; ++g) g4[g] = xwxb[g * HH + j];  // token 0 row
  } else {
#pragma unroll
    for (int g = 0; g < 4; ++g) g4[g] = bias[g * HH + j];
#pragma unroll 4
    for (int k = 0; k < HH; ++k) {
      float xv = embed[k];  // token 0 row
#pragma unroll
      for (int g = 0; g < 4; ++g) g4[g] += xv * Wx[(size_t)k * H4 + g * HH + j];
    }
  }
  float c1 = sigf(g4[0]) * tanhf(g4[2]);
  float h1 = sigf(g4[3]) * tanhf(c1);
  ws[O_CT + j * 32 + b] = c1;
  ws[O_HT + j * 32 + b] = h1;
  ws[O_PNT + j * 32 + b] = h1;
  ws[O_JOINT + j * 32 + b] = tanhf(tn[(size_t)b * TT * HH + j] + h1);
}

// ---------------- persistent decode kernel
__global__ __launch_bounds__(512) void decode_k(const float* __restrict__ tn,
                                                const float* __restrict__ embed,
                                                const float* __restrict__ Wx,
                                                const float* __restrict__ bias,
                                                const float* __restrict__ Wh,
                                                const float* __restrict__ Wc,
                                                const float* __restrict__ bc,
                                                float* __restrict__ out,
                                                float* ws, int use_table, int use_pack) {
  __shared__ float joint_s[20480];  // 80 KB: full 640x32 joint/h tile (per step)
  __shared__ float smem[10800];     // scratch overlay: part[8][32*36] / reduce / B scratch
  __shared__ float hwh_s[1056];     // gate: hwh[lc(32) stride 33][b]  (persists A->B)
  __shared__ float c_s[256];        // gate: c state (LDS-resident)
  __shared__ float pn_s[256];       // gate: out_PN state
  __shared__ int s_tok[32];
  __shared__ int s_upd[32];
  __shared__ int s_ptok[32];
  __shared__ float s_scores[32];
  const int tid = threadIdx.x, bid = blockIdx.x;
  unsigned* bar = (unsigned*)(ws + O_BAR);
  const float* xwxb = ws + O_XWXB;
  const bool is_log = (bid < NLOG);
  const bool is_gate = (bid >= NLOG) && (bid < NLOG + NGATE);
  const int q = bid - NLOG;  // gate slice index

  if (tid < 32) { s_ptok[tid] = 0; s_scores[tid] = 0.f; }
  if (is_gate && tid < 256) {
    const int jj = tid >> 5, b = tid & 31;
    c_s[jj * 32 + b] = ws[O_CT + (q * 8 + jj) * 32 + b];
    pn_s[jj * 32 + b] = ws[O_PNT + (q * 8 + jj) * 32 + b];
  }
  __syncthreads();

  // ---- GEMM thread decomposition: 8 cols x 4 batches per thread, 16-way K split
  const int lane = tid & 63, wvv = tid >> 6;
  const int sub = lane >> 5;          // K-split parity
  const int cg  = lane & 3;           // 4 col-groups of 8 contiguous cols
  const int bg  = (lane >> 2) & 7;    // 8 batch-groups of 4
  const int kb  = (wvv * 2 + sub) * 40;  // this thread's 40-row K chunk
  // weight base pointer (L2-resident, plain cached loads) + row stride
  const float* wbase;
  int wstride;
  if (is_log) {
    int c = bid * 32 + cg * 8;
    if (c > VV - 8) c = VV - 8;   // clamp (dup cols; masked at logits stage)
    wbase = Wc + (size_t)kb * VV + c;
    wstride = VV;
  } else if (use_pack) {
    // dense repacked slice: exact 128B lines, 80KB per gate -> L2-resident
    wbase = ws + O_WHP + ((size_t)q * HH + kb) * 32 + cg * 8;
    wstride = 32;
  } else {
    wbase = Wh + (size_t)kb * H4 + cg * HH + q * 8;
    wstride = H4;
  }
  const float* jb0 = joint_s + kb * 32 + bg * 4;

  unsigned epoch = 0;
  for (int t = 0; t < TT; ++t) {
    float tnv = 0.f;  // gate: tn[b][t+1][8q+jj], prefetched (held across barrier 1)

    // ================= phase A =================
    if (is_log || is_gate) {
      if (is_gate && tid < 256 && t + 1 < TT)
        tnv = tn[((size_t)(tid & 31) * TT + (t + 1)) * HH + q * 8 + (tid >> 5)];
      // stage the full 640x32 tile: one sc1 burst, one latency shot
      stage_sc1_full(joint_s, ws + (is_log ? O_JOINT : O_HT), tid);
      __syncthreads();

      float acc[32];  // acc[c*4+b]: 8 cols x 4 batches
#pragma unroll
      for (int i = 0; i < 32; ++i) acc[i] = 0.f;
      {
        const float* wp = wbase;
        const float* jp = jb0;
#pragma unroll 4
        for (int kk = 0; kk < 40; ++kk) {
          float4 w0 = *(const float4*)(wp);
          float4 w1 = *(const float4*)(wp + 4);
          float4 jv = *(const float4*)(jp);
          wp += wstride;
          jp += 32;
          acc[0]  += w0.x * jv.x; acc[1]  += w0.x * jv.y; acc[2]  += w0.x * jv.z; acc[3]  += w0.x * jv.w;
          acc[4]  += w0.y * jv.x; acc[5]  += w0.y * jv.y; acc[6]  += w0.y * jv.z; acc[7]  += w0.y * jv.w;
          acc[8]  += w0.z * jv.x; acc[9]  += w0.z * jv.y; acc[10] += w0.z * jv.z; acc[11] += w0.z * jv.w;
          acc[12] += w0.w * jv.x; acc[13] += w0.w * jv.y; acc[14] += w0.w * jv.z; acc[15] += w0.w * jv.w;
          acc[16] += w1.x * jv.x; acc[17] += w1.x * jv.y; acc[18] += w1.x * jv.z; acc[19] += w1.x * jv.w;
          acc[20] += w1.y * jv.x; acc[21] += w1.y * jv.y; acc[22] += w1.y * jv.z; acc[23] += w1.y * jv.w;
          acc[24] += w1.z * jv.x; acc[25] += w1.z * jv.y; acc[26] += w1.z * jv.z; acc[27] += w1.z * jv.w;
          acc[28] += w1.w * jv.x; acc[29] += w1.w * jv.y; acc[30] += w1.w * jv.z; acc[31] += w1.w * jv.w;
        }
      }
      // combine K-split pairs (sub 0/1) within the wave
#pragma unroll
      for (int i = 0; i < 32; ++i) acc[i] += __shfl_xor(acc[i], 32);
      float* part = smem;  // [8 waves][32 cols * 36]
      if (sub == 0) {
        float* pb = part + wvv * 1152 + bg * 4;
#pragma unroll
        for (int c = 0; c < 8; ++c)
          *(float4*)&pb[(cg * 8 + c) * 36] =
              make_float4(acc[c * 4 + 0], acc[c * 4 + 1], acc[c * 4 + 2], acc[c * 4 + 3]);
      }
      __syncthreads();

      const int b = tid & 31, colg = tid >> 5;
      if (is_log) {
        float* lm = smem + 9216;
        float* lsv = smem + 9744;
        int* lix = (int*)(smem + 10272);
        float m = -FLT_MAX; int ix = 0;
        float lv[2];
#pragma unroll
        for (int i = 0; i < 2; ++i) {
          const int cl = colg * 2 + i;
          float s = 0.f;
#pragma unroll
          for (int qq = 0; qq < 8; ++qq) s += part[qq * 1152 + cl * 36 + b];
          int cgl = bid * 32 + cl;
          float l = (cgl < VV) ? s + bc[cgl] : -FLT_MAX;
          lv[i] = l;
          if (l > m) { m = l; ix = cgl; }
        }
        float e = 0.f;
        if (m > -FLT_MAX) {
#pragma unroll
          for (int i = 0; i < 2; ++i) e += expf(lv[i] - m);
        }
        lm[colg * 33 + b] = m; lsv[colg * 33 + b] = e; lix[colg * 33 + b] = ix;
        __syncthreads();
        if (tid < 32) {
          float m2 = lm[tid], s2 = lsv[tid]; int ix2 = lix[tid];
#pragma unroll
          for (int qq = 1; qq < 16; ++qq) {
            float M = lm[qq * 33 + tid], S = lsv[qq * 33 + tid]; int I = lix[qq * 33 + tid];
            if (M > m2) { s2 = s2 * expf(m2 - M) + S; m2 = M; ix2 = I; }
            else if (M > -FLT_MAX) { s2 += S * expf(M - m2); }
          }
          stc1(&ws[O_PM + bid * 32 + tid], m2);                    // sc1 write-through
          stc1(&ws[O_PS + bid * 32 + tid], s2);
          stc1(&ws[O_PI + bid * 32 + tid], __int_as_float(ix2));
        }
      } else {
#pragma unroll
        for (int i = 0; i < 2; ++i) {
          const int cl = colg * 2 + i;
          float s = 0.f;
#pragma unroll
          for (int qq = 0; qq < 8; ++qq) s += part[qq * 1152 + cl * 36 + b];
          hwh_s[cl * 33 + b] = s;  // stays in LDS — no global round-trip
        }
      }
    }
    epoch++;
    grid_bar(bar, epoch);  // gate blocks read partials next (sc1 loads; no acquire)

    // ================= phase B (gate blocks only) =================
    if (is_gate) {
      float* rm = smem;               // [16*33]
      float* rs = smem + 528;
      int* ri = (int*)(smem + 1056);
      float* gmat = smem + 1584;      // [32*33]
      float* xl = smem + 2640;        // [32*161] fallback staging
      const int r = tid & 31, c16 = tid >> 5;
      {
        float m = -FLT_MAX, s = 0.f; int ix = 0;
#pragma unroll
        for (int i = 0; i < 10; ++i) {
          int idx = c16 * 10 + i;
          bool v = (idx < NLOG);
          int ic = v ? idx : 0;
          float M = ldc1(&ws[O_PM + ic * 32 + r]);               // sc1 reads
          float S = ldc1(&ws[O_PS + ic * 32 + r]);
          int I = __float_as_int(ldc1(&ws[O_PI + ic * 32 + r]));
          if (!v) { M = -FLT_MAX; S = 0.f; I = 0; }
          if (M > m) { s = s * expf(m - M) + S; m = M; ix = I; }
          else if (M > -FLT_MAX) { s += S * expf(M - m); }
        }
        rm[c16 * 33 + r] = m; rs[c16 * 33 + r] = s; ri[c16 * 33 + r] = ix;
      }
      __syncthreads();
      if (tid < 32) {
        float m = rm[tid], s = rs[tid]; int ix = ri[tid];
#pragma unroll
        for (int qq = 1; qq < 16; ++qq) {
          float M = rm[qq * 33 + tid], S = rs[qq * 33 + tid]; int I = ri[qq * 33 + tid];
          if (M > m) { s = s * expf(m - M) + S; m = M; ix = I; }
          else { s += S * expf(M - m); }
        }
        int pos = ix;
        int upd = (pos != 0) ? 1 : 0;
        int ntk = upd ? pos : s_ptok[tid];
        s_tok[tid] = ntk; s_upd[tid] = upd; s_ptok[tid] = ntk;
        if (bid == NLOG) {  // emitter
          float sc = s_scores[tid];
          if (upd) sc -= logf(s);
          s_scores[tid] = sc;
          out[BB + (size_t)tid * TT + t] = upd ? (float)pos : 0.0f;
          if (t == TT - 1) out[tid] = sc;
        }
      }
      __syncthreads();

      // gate pre-activations for the block's 32 strided cols
      const int b = tid & 31;
      float gv[2];
#pragma unroll
      for (int h = 0; h < 2; ++h) {
        int lc = (tid >> 5) + h * 16;
        int wcol = (lc >> 3) * HH + q * 8 + (lc & 7);
        float v = hwh_s[lc * 33 + b];
        if (use_table) v += xwxb[(size_t)s_tok[b] * H4 + wcol];
        else v += bias[wcol];
        gv[h] = v;
      }
      if (!use_table) {
        for (int st = 0; st < 4; ++st) {
          const int k0 = st * 160;
          __syncthreads();
          for (int i = tid; i < 32 * 160; i += 512) {
            int bb = i / 160, kk = i - bb * 160;
            xl[bb * 161 + kk] = embed[(size_t)s_tok[bb] * HH + k0 + kk];
          }
          __syncthreads();
          for (int k = 0; k < 160; ++k) {
            float xv = xl[b * 161 + k];
#pragma unroll
            for (int h = 0; h < 2; ++h) {
              int lc = (tid >> 5) + h * 16;
              int wcol = (lc >> 3) * HH + q * 8 + (lc & 7);
              gv[h] += xv * Wx[(size_t)(k0 + k) * H4 + wcol];
            }
          }
        }
      }
#pragma unroll
      for (int h = 0; h < 2; ++h) {
        int lc = (tid >> 5) + h * 16;
        gmat[lc * 33 + b] = gv[h];
      }
      __syncthreads();
      if (tid < 256) {
        const int jj = tid >> 5, b2 = tid & 31;
        float gi = gmat[(0 * 8 + jj) * 33 + b2];
        float gf = gmat[(1 * 8 + jj) * 33 + b2];
        float gg = gmat[(2 * 8 + jj) * 33 + b2];
        float go = gmat[(3 * 8 + jj) * 33 + b2];
        float cold = c_s[jj * 32 + b2];
        float c2 = sigf(gf) * cold + sigf(gi) * tanhf(gg);
        float h2 = sigf(go) * tanhf(c2);
        float pv;
        if (s_upd[b2]) {
          c_s[jj * 32 + b2] = c2;
          pn_s[jj * 32 + b2] = h2;
          stc1(&ws[O_HT + (q * 8 + jj) * 32 + b2], h2);   // sc1 write-through
          pv = h2;
        } else {
          pv = pn_s[jj * 32 + b2];
        }
        if (t + 1 < TT)
          stc1(&ws[O_JOINT + (q * 8 + jj) * 32 + b2], tanhf(tnv + pv));  // sc1
      }
    }
    epoch++;
    grid_bar(bar, epoch);  // next A stages jointT / hT (sc1 bursts; no acquire)
  }
}

extern "C" void kernel_launch(void* const* d_in, const int* in_sizes, int n_in,
                              void* d_out, int out_size, void* d_ws, size_t ws_size,
                              hipStream_t stream) {
  const float* tn    = (const float*)d_in[0];
  const float* embed = (const float*)d_in[1];
  const float* Wx    = (const float*)d_in[2];
  const float* Wh    = (const float*)d_in[3];
  const float* bias  = (const float*)d_in[4];
  const float* Wc    = (const float*)d_in[5];
  const float* bc    = (const float*)d_in[6];
  float* out = (float*)d_out;
  float* ws  = (float*)d_ws;

  const size_t need_table = (size_t)(O_XWXB + XWXB_ELEMS) * sizeof(float);
  const size_t need_pack  = (size_t)(O_WHP + WHP_ELEMS) * sizeof(float);
  const int use_table = (ws_size >= need_table) ? 1 : 0;
  const int use_pack  = (ws_size >= need_pack) ? 1 : 0;

  if (use_table)
    hipLaunchKernelGGL(precompute_k, dim3(10, 313), dim3(256), 0, stream,
                       embed, Wx, bias, ws + O_XWXB);
  if (use_pack)
    hipLaunchKernelGGL(repack_k, dim3(NGATE), dim3(256), 0, stream, Wh, ws + O_WHP);
  hipLaunchKernelGGL(init_k, dim3(80), dim3(256), 0, stream, tn, embed, Wx, bias, ws, use_table);
  hipLaunchKernelGGL(decode_k, dim3(NB), dim3(512), 0, stream,
                     tn, embed, Wx, bias, Wh, Wc, bc, out, ws, use_table, use_pack);
}